// Round 1
// baseline (50.505 us; speedup 1.0000x reference)
//
#include <hip/hip_runtime.h>

// Path signature, depth 4, N=64, L=512, C=8.
// Output per batch: [sig1(8) | sig2(64) | sig3(512) | sig4(4096)] = 4680 f32.
//
// Chen-step factorization => fully thread-private scan state:
//   new4[ijkl] = s4 + d_l*( s3 + s2*dk/2 + s1*dj*dk/6 + di*dj*dk/24 )
//   new3[ijk]  = s3 + dk*( s2 + s1*dj/2 + di*dj/6 )
//   new2[ij]   = s2 + dj*( s1 + di/2 )
//   new1[i]    = s1 + di
// Each thread owns one (i,j,k) triple + 4 l-values; replicates s1,s2,s3.
// No barriers / no cross-thread comms inside the 511-step loop.

static constexpr int L = 512;
static constexpr int NC = 8;
static constexpr int NSEG = L - 1;                      // 511
static constexpr int OUT_STRIDE = 8 + 64 + 512 + 4096;  // 4680

__global__ __launch_bounds__(256) void sig_kernel(const float* __restrict__ path,
                                                  float* __restrict__ out) {
    __shared__ float dx[NSEG * NC];  // 16352 B
    const int t = threadIdx.x;
    const int blk = blockIdx.x;
    const int n = blk >> 2;      // batch index (4 blocks per batch)
    const int part = blk & 3;
    const float* p = path + (size_t)n * (L * NC);

    // Stage increments: dx[e] = path[n][e/8+1][e%8] - path[n][e/8][e%8]
    for (int e = t; e < NSEG * NC; e += 256)
        dx[e] = p[e + NC] - p[e];
    __syncthreads();

    const int idx = part * 256 + t;   // 0..1023 within batch
    const int tri = idx >> 1;         // (i,j,k) in [0,512)
    const int lh = (idx & 1) << 2;    // l base: 0 or 4
    const int i = tri >> 6;
    const int j = (tri >> 3) & 7;
    const int k = tri & 7;

    float s1 = 0.f, s2 = 0.f, s3 = 0.f;
    float s40 = 0.f, s41 = 0.f, s42 = 0.f, s43 = 0.f;

    constexpr float c2 = 0.5f;
    constexpr float c3 = 1.f / 6.f;
    constexpr float c4 = 1.f / 24.f;

    const float* d = dx;
#pragma unroll 2
    for (int s = 0; s < NSEG; ++s, d += NC) {
        const float di = d[i];
        const float dj = d[j];
        const float dk = d[k];
        const float4 dl = *reinterpret_cast<const float4*>(d + lh);

        const float pij = di * dj;
        const float djk = dj * dk;

        // level-4 coefficient (uses OLD s1,s2,s3)
        const float u = fmaf(s1, c3, di * c4);        // s1/6 + di/24
        float Cc = fmaf(s2, dk * c2, s3);             // s3 + s2*dk/2
        Cc = fmaf(djk, u, Cc);                        // + dj*dk*(s1/6+di/24)
        s40 = fmaf(dl.x, Cc, s40);
        s41 = fmaf(dl.y, Cc, s41);
        s42 = fmaf(dl.z, Cc, s42);
        s43 = fmaf(dl.w, Cc, s43);

        // level-3 (old s1,s2)
        float v = fmaf(s1, dj * c2, s2);              // s2 + s1*dj/2
        v = fmaf(pij, c3, v);                         // + di*dj/6
        s3 = fmaf(dk, v, s3);

        // level-2 (old s1)
        s2 = fmaf(dj, fmaf(di, c2, s1), s2);

        // level-1
        s1 += di;
    }

    float* o = out + (size_t)n * OUT_STRIDE;
    // level 4: 4 contiguous floats at 584 + tri*8 + lh (16B aligned)
    float4 r;
    r.x = s40; r.y = s41; r.z = s42; r.w = s43;
    *reinterpret_cast<float4*>(o + 584 + tri * 8 + lh) = r;
    if (lh == 0) {
        o[72 + tri] = s3;                 // level 3
        if (k == 0) {
            o[8 + (tri >> 3)] = s2;       // level 2
            if (j == 0) o[i] = s1;        // level 1
        }
    }
}

extern "C" void kernel_launch(void* const* d_in, const int* in_sizes, int n_in,
                              void* d_out, int out_size, void* d_ws, size_t ws_size,
                              hipStream_t stream) {
    const float* path = (const float*)d_in[0];
    float* out = (float*)d_out;
    // 64 batches * 4 blocks each = 256 blocks of 256 threads
    sig_kernel<<<256, 256, 0, stream>>>(path, out);
}

// Round 2
// 43.264 us; speedup vs baseline: 1.1674x; 1.1674x over previous
//
#include <hip/hip_runtime.h>

// Depth-4 path signature, N=64, L=512, C=8. Output/batch:
// [sig1(8) | sig2(64) | sig3(512) | sig4(4096)] = 4680 f32.
//
// Two-level scan (Chen's identity is associative):
//  K1: 16 chunks of ~32 segments scanned independently -> chunk sigs in ws.
//      Thread = one (i,j,k) triple, owns all 8 l-accumulators. Per-step state
//      update is fully thread-private (replicated s1,s2,s3):
//        s4[l] += d_l*( s3 + s2*dk/2 + s1*dj*dk/6 + di*dj*dk/24 )
//        s3    += dk*( s2 + s1*dj/2 + di*dj/6 )
//        s2    += dj*( s1 + di/2 );  s1 += di
//      dj,dk come from cndmask-select over the two broadcast b128 LDS reads
//      (keeps the per-CU LDS pipe off the critical path; VALU has slack).
//  K2: per batch, fold the 16 chunk sigs left-to-right:
//        n4 = A4+B4+A3*B1[l]+A2*B2[kl]+A1*B3[jkl]; n3 = A3+B3+A2*B1[k]+A1*B2[jk]
//        n2 = A2+B2+A1*B1[j]; n1 = A1+B1
//      Prefix state stays thread-private with the same (i,j,k) ownership.

static constexpr int L = 512;
static constexpr int NC = 8;
static constexpr int NSEG = L - 1;               // 511
static constexpr int SIG = 8 + 64 + 512 + 4096;  // 4680
static constexpr int NB = 64;

__device__ __forceinline__ float sel8(float d0, float d1, float d2, float d3,
                                      float d4, float d5, float d6, float d7,
                                      bool b0, bool b1, bool b2) {
    float x0 = b0 ? d1 : d0;
    float x1 = b0 ? d3 : d2;
    float x2 = b0 ? d5 : d4;
    float x3 = b0 ? d7 : d6;
    float y0 = b1 ? x1 : x0;
    float y1 = b1 ? x3 : x2;
    return b2 ? y1 : y0;
}

template <int CH>
__global__ __launch_bounds__(256) void sig_chunk(const float* __restrict__ path,
                                                 float* __restrict__ ws) {
    constexpr int SEGP = (NSEG + CH - 1) / CH;
    __shared__ float dx[SEGP * NC];
    const int t = threadIdx.x;
    const int blk = blockIdx.x;
    const int sub = blk & 1;
    const int c = (blk >> 1) % CH;
    const int n = blk / (2 * CH);
    const int seg0 = c * SEGP;
    const int len = min(SEGP, NSEG - seg0);
    const float* p = path + (size_t)n * (L * NC) + (size_t)seg0 * NC;

    for (int e = t; e < len * NC; e += 256)
        dx[e] = p[e + NC] - p[e];
    __syncthreads();

    const int tri = sub * 256 + t;
    const int i = tri >> 6;
    const int j = (tri >> 3) & 7;
    const int k = tri & 7;
    const bool jb0 = j & 1, jb1 = j & 2, jb2 = j & 4;
    const bool kb0 = k & 1, kb1 = k & 2, kb2 = k & 4;

    float s1 = 0.f, s2 = 0.f, s3 = 0.f;
    float4 v0 = {0.f, 0.f, 0.f, 0.f};
    float4 v1 = {0.f, 0.f, 0.f, 0.f};
    constexpr float c3 = 1.f / 6.f;
    constexpr float c4 = 1.f / 24.f;

    const float* d = dx;
#pragma unroll 4
    for (int s = 0; s < len; ++s, d += NC) {
        const float di = d[i];                      // wave-uniform broadcast
        const float4 A = *reinterpret_cast<const float4*>(d);
        const float4 B = *reinterpret_cast<const float4*>(d + 4);
        const float dj = sel8(A.x, A.y, A.z, A.w, B.x, B.y, B.z, B.w, jb0, jb1, jb2);
        const float dk = sel8(A.x, A.y, A.z, A.w, B.x, B.y, B.z, B.w, kb0, kb1, kb2);

        const float djk = dj * dk;
        const float u = fmaf(s1, c3, di * c4);       // s1/6 + di/24
        float Cc = fmaf(s2, dk * 0.5f, s3);          // s3 + s2*dk/2
        Cc = fmaf(djk, u, Cc);

        v0.x = fmaf(A.x, Cc, v0.x);
        v0.y = fmaf(A.y, Cc, v0.y);
        v0.z = fmaf(A.z, Cc, v0.z);
        v0.w = fmaf(A.w, Cc, v0.w);
        v1.x = fmaf(B.x, Cc, v1.x);
        v1.y = fmaf(B.y, Cc, v1.y);
        v1.z = fmaf(B.z, Cc, v1.z);
        v1.w = fmaf(B.w, Cc, v1.w);

        float v = fmaf(s1, dj * 0.5f, s2);
        v = fmaf(di * dj, c3, v);
        s3 = fmaf(dk, v, s3);
        s2 = fmaf(dj, fmaf(di, 0.5f, s1), s2);
        s1 += di;
    }

    float* o = ws + ((size_t)n * CH + c) * SIG;
    *reinterpret_cast<float4*>(o + 584 + tri * 8) = v0;
    *reinterpret_cast<float4*>(o + 584 + tri * 8 + 4) = v1;
    o[72 + tri] = s3;
    if (k == 0) {
        o[8 + (tri >> 3)] = s2;
        if (j == 0) o[i] = s1;
    }
}

template <int CH>
__global__ __launch_bounds__(256) void sig_combine(const float* __restrict__ ws,
                                                   float* __restrict__ out) {
    const int t = threadIdx.x;
    const int blk = blockIdx.x;     // NB*2 blocks
    const int sub = blk & 1;
    const int n = blk >> 1;
    const int tri = sub * 256 + t;
    const int i = tri >> 6;
    const int j = (tri >> 3) & 7;
    const int k = tri & 7;

    const float* Bs = ws + (size_t)n * CH * SIG;

    // init prefix state from chunk 0
    float a1 = Bs[i];
    float a2 = Bs[8 + (tri >> 3)];
    float a3 = Bs[72 + tri];
    float4 a40 = *reinterpret_cast<const float4*>(Bs + 584 + tri * 8);
    float4 a41 = *reinterpret_cast<const float4*>(Bs + 584 + tri * 8 + 4);

#pragma unroll 3
    for (int c = 1; c < CH; ++c) {
        const float* Bc = Bs + (size_t)c * SIG;
        const float b1i = Bc[i];
        const float b1j = Bc[j];
        const float b1k = Bc[k];
        const float4 l0 = *reinterpret_cast<const float4*>(Bc);        // B1[0:4]
        const float4 l1 = *reinterpret_cast<const float4*>(Bc + 4);    // B1[4:8]
        const float b2ij = Bc[8 + (tri >> 3)];
        const float b2jk = Bc[8 + j * 8 + k];
        const float4 k0 = *reinterpret_cast<const float4*>(Bc + 8 + k * 8);
        const float4 k1 = *reinterpret_cast<const float4*>(Bc + 8 + k * 8 + 4);
        const float b3ijk = Bc[72 + tri];
        const float4 m0 = *reinterpret_cast<const float4*>(Bc + 72 + j * 64 + k * 8);
        const float4 m1 = *reinterpret_cast<const float4*>(Bc + 72 + j * 64 + k * 8 + 4);
        const float4 f0 = *reinterpret_cast<const float4*>(Bc + 584 + tri * 8);
        const float4 f1 = *reinterpret_cast<const float4*>(Bc + 584 + tri * 8 + 4);

        // level 4 (old a1,a2,a3)
        a40.x = fmaf(a3, l0.x, fmaf(a2, k0.x, fmaf(a1, m0.x, a40.x + f0.x)));
        a40.y = fmaf(a3, l0.y, fmaf(a2, k0.y, fmaf(a1, m0.y, a40.y + f0.y)));
        a40.z = fmaf(a3, l0.z, fmaf(a2, k0.z, fmaf(a1, m0.z, a40.z + f0.z)));
        a40.w = fmaf(a3, l0.w, fmaf(a2, k0.w, fmaf(a1, m0.w, a40.w + f0.w)));
        a41.x = fmaf(a3, l1.x, fmaf(a2, k1.x, fmaf(a1, m1.x, a41.x + f1.x)));
        a41.y = fmaf(a3, l1.y, fmaf(a2, k1.y, fmaf(a1, m1.y, a41.y + f1.y)));
        a41.z = fmaf(a3, l1.z, fmaf(a2, k1.z, fmaf(a1, m1.z, a41.z + f1.z)));
        a41.w = fmaf(a3, l1.w, fmaf(a2, k1.w, fmaf(a1, m1.w, a41.w + f1.w)));
        // level 3
        a3 = fmaf(a2, b1k, fmaf(a1, b2jk, a3 + b3ijk));
        // level 2
        a2 = fmaf(a1, b1j, a2 + b2ij);
        // level 1
        a1 += b1i;
    }

    float* o = out + (size_t)n * SIG;
    *reinterpret_cast<float4*>(o + 584 + tri * 8) = a40;
    *reinterpret_cast<float4*>(o + 584 + tri * 8 + 4) = a41;
    o[72 + tri] = a3;
    if (k == 0) {
        o[8 + (tri >> 3)] = a2;
        if (j == 0) o[i] = a1;
    }
}

// --- fallback (round-1 kernel) if workspace is too small -------------------
__global__ __launch_bounds__(256) void sig_kernel(const float* __restrict__ path,
                                                  float* __restrict__ out) {
    __shared__ float dx[NSEG * NC];
    const int t = threadIdx.x;
    const int blk = blockIdx.x;
    const int n = blk >> 2;
    const int part = blk & 3;
    const float* p = path + (size_t)n * (L * NC);
    for (int e = t; e < NSEG * NC; e += 256)
        dx[e] = p[e + NC] - p[e];
    __syncthreads();

    const int idx = part * 256 + t;
    const int tri = idx >> 1;
    const int lh = (idx & 1) << 2;
    const int i = tri >> 6;
    const int j = (tri >> 3) & 7;
    const int k = tri & 7;

    float s1 = 0.f, s2 = 0.f, s3 = 0.f;
    float s40 = 0.f, s41 = 0.f, s42 = 0.f, s43 = 0.f;
    constexpr float c3 = 1.f / 6.f;
    constexpr float c4 = 1.f / 24.f;

    const float* d = dx;
#pragma unroll 2
    for (int s = 0; s < NSEG; ++s, d += NC) {
        const float di = d[i];
        const float dj = d[j];
        const float dk = d[k];
        const float4 dl = *reinterpret_cast<const float4*>(d + lh);
        const float djk = dj * dk;
        const float u = fmaf(s1, c3, di * c4);
        float Cc = fmaf(s2, dk * 0.5f, s3);
        Cc = fmaf(djk, u, Cc);
        s40 = fmaf(dl.x, Cc, s40);
        s41 = fmaf(dl.y, Cc, s41);
        s42 = fmaf(dl.z, Cc, s42);
        s43 = fmaf(dl.w, Cc, s43);
        float v = fmaf(s1, dj * 0.5f, s2);
        v = fmaf(di * dj, c3, v);
        s3 = fmaf(dk, v, s3);
        s2 = fmaf(dj, fmaf(di, 0.5f, s1), s2);
        s1 += di;
    }

    float* o = out + (size_t)n * SIG;
    float4 r;
    r.x = s40; r.y = s41; r.z = s42; r.w = s43;
    *reinterpret_cast<float4*>(o + 584 + tri * 8 + lh) = r;
    if (lh == 0) {
        o[72 + tri] = s3;
        if (k == 0) {
            o[8 + (tri >> 3)] = s2;
            if (j == 0) o[i] = s1;
        }
    }
}

extern "C" void kernel_launch(void* const* d_in, const int* in_sizes, int n_in,
                              void* d_out, int out_size, void* d_ws, size_t ws_size,
                              hipStream_t stream) {
    const float* path = (const float*)d_in[0];
    float* out = (float*)d_out;
    float* ws = (float*)d_ws;

    const size_t need16 = (size_t)NB * 16 * SIG * sizeof(float);  // ~19.2 MB
    const size_t need4 = (size_t)NB * 4 * SIG * sizeof(float);    // ~4.8 MB

    if (ws_size >= need16) {
        sig_chunk<16><<<NB * 16 * 2, 256, 0, stream>>>(path, ws);
        sig_combine<16><<<NB * 2, 256, 0, stream>>>(ws, out);
    } else if (ws_size >= need4) {
        sig_chunk<4><<<NB * 4 * 2, 256, 0, stream>>>(path, ws);
        sig_combine<4><<<NB * 2, 256, 0, stream>>>(ws, out);
    } else {
        sig_kernel<<<256, 256, 0, stream>>>(path, out);
    }
}

// Round 3
// 35.714 us; speedup vs baseline: 1.4141x; 1.2114x over previous
//
#include <hip/hip_runtime.h>

// Depth-4 path signature, N=64, L=512, C=8. Output/batch:
// [sig1(8) | sig2(64) | sig3(512) | sig4(4096)] = 4680 f32.
//
// K1 sig_chunk2: 16 chunks of ~32 segments scanned independently.
//   - NO LDS: per-step increments are wave-uniform -> two uniform float4
//     global loads of path rows (L1-resident), dx formed in registers,
//     di/dj/dk extracted via cndmask select trees.
//   - 2 triples per thread (shared (i,j), k-pair): 256 threads cover 512
//     triples; 64*16 = 1024 blocks -> 16 waves/CU, pure VALU-bound.
// K2 sig_fold: per batch, fold the 16 chunk sigs left-to-right (Chen):
//   n4 = A4+B4+A3*B1[l]+A2*B2[kl]+A1*B3[jkl]; n3 = A3+B3+A2*B1[k]+A1*B2[jk]
//   n2 = A2+B2+A1*B1[j]; n1 = A1+B1
//   Depth-2 register prefetch (named A/B sets, static indexing) hides the
//   scattered L2 gather latency behind the fold VALU.

static constexpr int L = 512;
static constexpr int NC = 8;
static constexpr int NSEG = L - 1;               // 511
static constexpr int SIG = 8 + 64 + 512 + 4096;  // 4680
static constexpr int NB = 64;

__device__ __forceinline__ float sel8(float d0, float d1, float d2, float d3,
                                      float d4, float d5, float d6, float d7,
                                      bool b0, bool b1, bool b2) {
    float x0 = b0 ? d1 : d0;
    float x1 = b0 ? d3 : d2;
    float x2 = b0 ? d5 : d4;
    float x3 = b0 ? d7 : d6;
    float y0 = b1 ? x1 : x0;
    float y1 = b1 ? x3 : x2;
    return b2 ? y1 : y0;
}

template <int CH>
__global__ __launch_bounds__(256) void sig_chunk2(const float* __restrict__ path,
                                                  float* __restrict__ ws) {
    constexpr int SEGP = (NSEG + CH - 1) / CH;
    const int t = threadIdx.x;
    const int c = blockIdx.x % CH;
    const int n = blockIdx.x / CH;
    const int seg0 = c * SEGP;
    const int len = min(SEGP, NSEG - seg0);
    const float* p = path + (size_t)n * (L * NC) + (size_t)seg0 * NC;

    // thread owns triples 2t, 2t+1: i = t>>5, j = (t>>2)&7, k0 = (t&3)*2, k1 = k0+1
    const bool i0 = t & 32, i1 = t & 64, i2 = t & 128;
    const bool j0 = t & 4, j1 = t & 8, j2 = t & 16;
    const bool kb0 = t & 1, kb1 = t & 2;

    float s1 = 0.f, s2 = 0.f, s3a = 0.f, s3b = 0.f;
    float4 va0 = {0, 0, 0, 0}, va1 = {0, 0, 0, 0};
    float4 vb0 = {0, 0, 0, 0}, vb1 = {0, 0, 0, 0};
    constexpr float c3 = 1.f / 6.f;
    constexpr float c4 = 1.f / 24.f;

    float4 p0 = *reinterpret_cast<const float4*>(p);
    float4 p1 = *reinterpret_cast<const float4*>(p + 4);
#pragma unroll 4
    for (int s = 0; s < len; ++s) {
        const float4 q0 = *reinterpret_cast<const float4*>(p + (s + 1) * 8);
        const float4 q1 = *reinterpret_cast<const float4*>(p + (s + 1) * 8 + 4);
        const float d0 = q0.x - p0.x, d1 = q0.y - p0.y;
        const float d2 = q0.z - p0.z, d3 = q0.w - p0.w;
        const float d4 = q1.x - p1.x, d5 = q1.y - p1.y;
        const float d6 = q1.z - p1.z, d7 = q1.w - p1.w;
        p0 = q0;
        p1 = q1;

        const float di = sel8(d0, d1, d2, d3, d4, d5, d6, d7, i0, i1, i2);
        const float dj = sel8(d0, d1, d2, d3, d4, d5, d6, d7, j0, j1, j2);
        const float xa = kb0 ? d2 : d0, xb = kb0 ? d6 : d4;
        const float dk0 = kb1 ? xb : xa;
        const float ya = kb0 ? d3 : d1, yb = kb0 ? d7 : d5;
        const float dk1 = kb1 ? yb : ya;

        const float u = fmaf(s1, c3, di * c4);     // s1/6 + di/24
        float vv = fmaf(s1, dj * 0.5f, s2);        // s2 + s1*dj/2
        vv = fmaf(di * dj, c3, vv);                // + di*dj/6

        float Cc0 = fmaf(s2, dk0 * 0.5f, s3a);
        Cc0 = fmaf(dj * dk0, u, Cc0);
        float Cc1 = fmaf(s2, dk1 * 0.5f, s3b);
        Cc1 = fmaf(dj * dk1, u, Cc1);

        va0.x = fmaf(d0, Cc0, va0.x);
        va0.y = fmaf(d1, Cc0, va0.y);
        va0.z = fmaf(d2, Cc0, va0.z);
        va0.w = fmaf(d3, Cc0, va0.w);
        va1.x = fmaf(d4, Cc0, va1.x);
        va1.y = fmaf(d5, Cc0, va1.y);
        va1.z = fmaf(d6, Cc0, va1.z);
        va1.w = fmaf(d7, Cc0, va1.w);
        vb0.x = fmaf(d0, Cc1, vb0.x);
        vb0.y = fmaf(d1, Cc1, vb0.y);
        vb0.z = fmaf(d2, Cc1, vb0.z);
        vb0.w = fmaf(d3, Cc1, vb0.w);
        vb1.x = fmaf(d4, Cc1, vb1.x);
        vb1.y = fmaf(d5, Cc1, vb1.y);
        vb1.z = fmaf(d6, Cc1, vb1.z);
        vb1.w = fmaf(d7, Cc1, vb1.w);

        s3a = fmaf(dk0, vv, s3a);
        s3b = fmaf(dk1, vv, s3b);
        s2 = fmaf(dj, fmaf(di, 0.5f, s1), s2);
        s1 += di;
    }

    float* o = ws + ((size_t)n * CH + c) * SIG;
    float* o4 = o + 584 + t * 16;  // triples 2t,2t+1 -> 16 contiguous floats
    *reinterpret_cast<float4*>(o4) = va0;
    *reinterpret_cast<float4*>(o4 + 4) = va1;
    *reinterpret_cast<float4*>(o4 + 8) = vb0;
    *reinterpret_cast<float4*>(o4 + 12) = vb1;
    o[72 + 2 * t] = s3a;
    o[72 + 2 * t + 1] = s3b;
    if ((t & 3) == 0) {
        o[8 + (t >> 2)] = s2;
        if ((t & 31) == 0) o[t >> 5] = s1;
    }
}

template <int CH>
__global__ __launch_bounds__(256) void sig_fold(const float* __restrict__ ws,
                                                float* __restrict__ out) {
    const int t = threadIdx.x;
    const int sub = blockIdx.x & 1;
    const int n = blockIdx.x >> 1;
    const int tri = sub * 256 + t;
    const int i = tri >> 6;
    const int j = (tri >> 3) & 7;
    const int k = tri & 7;
    const float* Bs = ws + (size_t)n * CH * SIG;

    float a1 = Bs[i];
    float a2 = Bs[8 + (tri >> 3)];
    float a3 = Bs[72 + tri];
    float4 a40 = *reinterpret_cast<const float4*>(Bs + 584 + tri * 8);
    float4 a41 = *reinterpret_cast<const float4*>(Bs + 584 + tri * 8 + 4);

    float Ab1i, Ab1j, Ab1k, Ab2ij, Ab2jk, Ab3;
    float4 Al0, Al1, Ak0, Ak1, Am0, Am1, Af0, Af1;
    float Bb1i, Bb1j, Bb1k, Bb2ij, Bb2jk, Bb3;
    float4 Bl0, Bl1, Bk0, Bk1, Bm0, Bm1, Bf0, Bf1;

#define LOADSET(P, cidx)                                                      \
    {                                                                         \
        const float* Bc = Bs + (size_t)(cidx)*SIG;                            \
        P##b1i = Bc[i];                                                       \
        P##b1j = Bc[j];                                                       \
        P##b1k = Bc[k];                                                       \
        P##l0 = *reinterpret_cast<const float4*>(Bc);                         \
        P##l1 = *reinterpret_cast<const float4*>(Bc + 4);                     \
        P##b2ij = Bc[8 + (tri >> 3)];                                         \
        P##b2jk = Bc[8 + j * 8 + k];                                          \
        P##k0 = *reinterpret_cast<const float4*>(Bc + 8 + k * 8);             \
        P##k1 = *reinterpret_cast<const float4*>(Bc + 8 + k * 8 + 4);         \
        P##b3 = Bc[72 + tri];                                                 \
        P##m0 = *reinterpret_cast<const float4*>(Bc + 72 + j * 64 + k * 8);   \
        P##m1 = *reinterpret_cast<const float4*>(Bc + 72 + j * 64 + k * 8 + 4); \
        P##f0 = *reinterpret_cast<const float4*>(Bc + 584 + tri * 8);         \
        P##f1 = *reinterpret_cast<const float4*>(Bc + 584 + tri * 8 + 4);     \
    }

#define FOLD(P)                                                                     \
    {                                                                               \
        a40.x = fmaf(a3, P##l0.x, fmaf(a2, P##k0.x, fmaf(a1, P##m0.x, a40.x + P##f0.x))); \
        a40.y = fmaf(a3, P##l0.y, fmaf(a2, P##k0.y, fmaf(a1, P##m0.y, a40.y + P##f0.y))); \
        a40.z = fmaf(a3, P##l0.z, fmaf(a2, P##k0.z, fmaf(a1, P##m0.z, a40.z + P##f0.z))); \
        a40.w = fmaf(a3, P##l0.w, fmaf(a2, P##k0.w, fmaf(a1, P##m0.w, a40.w + P##f0.w))); \
        a41.x = fmaf(a3, P##l1.x, fmaf(a2, P##k1.x, fmaf(a1, P##m1.x, a41.x + P##f1.x))); \
        a41.y = fmaf(a3, P##l1.y, fmaf(a2, P##k1.y, fmaf(a1, P##m1.y, a41.y + P##f1.y))); \
        a41.z = fmaf(a3, P##l1.z, fmaf(a2, P##k1.z, fmaf(a1, P##m1.z, a41.z + P##f1.z))); \
        a41.w = fmaf(a3, P##l1.w, fmaf(a2, P##k1.w, fmaf(a1, P##m1.w, a41.w + P##f1.w))); \
        a3 = fmaf(a2, P##b1k, fmaf(a1, P##b2jk, a3 + P##b3));                       \
        a2 = fmaf(a1, P##b1j, a2 + P##b2ij);                                        \
        a1 += P##b1i;                                                               \
    }

    LOADSET(A, 1);
    if (CH > 2) LOADSET(B, 2);
#pragma unroll
    for (int c = 1; c <= CH - 1; ++c) {
        if (c & 1) {
            FOLD(A);
            if (c + 2 <= CH - 1) LOADSET(A, c + 2);
        } else {
            FOLD(B);
            if (c + 2 <= CH - 1) LOADSET(B, c + 2);
        }
    }
#undef LOADSET
#undef FOLD

    float* o = out + (size_t)n * SIG;
    *reinterpret_cast<float4*>(o + 584 + tri * 8) = a40;
    *reinterpret_cast<float4*>(o + 584 + tri * 8 + 4) = a41;
    o[72 + tri] = a3;
    if (k == 0) {
        o[8 + (tri >> 3)] = a2;
        if (j == 0) o[i] = a1;
    }
}

// --- fallback (round-1 kernel) if workspace is too small -------------------
__global__ __launch_bounds__(256) void sig_kernel(const float* __restrict__ path,
                                                  float* __restrict__ out) {
    __shared__ float dx[NSEG * NC];
    const int t = threadIdx.x;
    const int blk = blockIdx.x;
    const int n = blk >> 2;
    const int part = blk & 3;
    const float* p = path + (size_t)n * (L * NC);
    for (int e = t; e < NSEG * NC; e += 256)
        dx[e] = p[e + NC] - p[e];
    __syncthreads();

    const int idx = part * 256 + t;
    const int tri = idx >> 1;
    const int lh = (idx & 1) << 2;
    const int i = tri >> 6;
    const int j = (tri >> 3) & 7;
    const int k = tri & 7;

    float s1 = 0.f, s2 = 0.f, s3 = 0.f;
    float s40 = 0.f, s41 = 0.f, s42 = 0.f, s43 = 0.f;
    constexpr float c3 = 1.f / 6.f;
    constexpr float c4 = 1.f / 24.f;

    const float* d = dx;
#pragma unroll 2
    for (int s = 0; s < NSEG; ++s, d += NC) {
        const float di = d[i];
        const float dj = d[j];
        const float dk = d[k];
        const float4 dl = *reinterpret_cast<const float4*>(d + lh);
        const float djk = dj * dk;
        const float u = fmaf(s1, c3, di * c4);
        float Cc = fmaf(s2, dk * 0.5f, s3);
        Cc = fmaf(djk, u, Cc);
        s40 = fmaf(dl.x, Cc, s40);
        s41 = fmaf(dl.y, Cc, s41);
        s42 = fmaf(dl.z, Cc, s42);
        s43 = fmaf(dl.w, Cc, s43);
        float v = fmaf(s1, dj * 0.5f, s2);
        v = fmaf(di * dj, c3, v);
        s3 = fmaf(dk, v, s3);
        s2 = fmaf(dj, fmaf(di, 0.5f, s1), s2);
        s1 += di;
    }

    float* o = out + (size_t)n * SIG;
    float4 r;
    r.x = s40; r.y = s41; r.z = s42; r.w = s43;
    *reinterpret_cast<float4*>(o + 584 + tri * 8 + lh) = r;
    if (lh == 0) {
        o[72 + tri] = s3;
        if (k == 0) {
            o[8 + (tri >> 3)] = s2;
            if (j == 0) o[i] = s1;
        }
    }
}

extern "C" void kernel_launch(void* const* d_in, const int* in_sizes, int n_in,
                              void* d_out, int out_size, void* d_ws, size_t ws_size,
                              hipStream_t stream) {
    const float* path = (const float*)d_in[0];
    float* out = (float*)d_out;
    float* ws = (float*)d_ws;

    const size_t need16 = (size_t)NB * 16 * SIG * sizeof(float);  // ~19.2 MB
    const size_t need4 = (size_t)NB * 4 * SIG * sizeof(float);    // ~4.8 MB

    if (ws_size >= need16) {
        sig_chunk2<16><<<NB * 16, 256, 0, stream>>>(path, ws);
        sig_fold<16><<<NB * 2, 256, 0, stream>>>(ws, out);
    } else if (ws_size >= need4) {
        sig_chunk2<4><<<NB * 4, 256, 0, stream>>>(path, ws);
        sig_fold<4><<<NB * 2, 256, 0, stream>>>(ws, out);
    } else {
        sig_kernel<<<256, 256, 0, stream>>>(path, out);
    }
}